// Round 7
// baseline (210.135 us; speedup 1.0000x reference)
//
#include <hip/hip_runtime.h>
#include <hip/hip_bf16.h>

typedef __bf16 bf16x8 __attribute__((ext_vector_type(8)));
typedef short short8 __attribute__((ext_vector_type(8)));
typedef float f32x4 __attribute__((ext_vector_type(4)));
typedef unsigned short ushort_t;

#define T_LEN 32768
#define B_SZ 4
#define NSLOW 2047
#define NSEQ (B_SZ * NSLOW)   // 8188
#define GH 64
#define G3 192
#define NL 4
#define HID 32
#define NCH 256               // fast-path chunks per batch (len 128)
#define L2E 1.44269504088896341f
#define CONV_PAD_BYTES 470656 // ws layout anchor (kept from staged design)

static __device__ __forceinline__ float bf2f(ushort_t u) {
    union { unsigned u; float f; } c; c.u = ((unsigned)u) << 16; return c.f;
}
static __device__ __forceinline__ ushort_t f2bf(float f) {
    union { float f; unsigned u; } c; c.f = f;
    unsigned r = (c.u + 0x7FFFu + ((c.u >> 16) & 1u)) >> 16;
    return (ushort_t)r;
}
static __device__ __forceinline__ unsigned pk2bf(float a, float b) {
    float2 f; f.x = a; f.y = b;
    __hip_bfloat162 h = __float22bfloat162_rn(f);   // v_cvt_pk_bf16_f32
    unsigned u;
    __builtin_memcpy(&u, &h, 4);
    return u;
}
static __device__ __forceinline__ f32x4 mfma16(short8 a, short8 b, f32x4 c) {
    return __builtin_amdgcn_mfma_f32_16x16x32_bf16(
        __builtin_bit_cast(bf16x8, a), __builtin_bit_cast(bf16x8, b), c, 0, 0, 0);
}
// LDS layout: short off = ((t*8 + kb)*16 + (seq ^ (kb&7)))*8 + i
static __device__ __forceinline__ int xoff(int t, int kb, int seq) {
    return ((((t << 3) + kb) << 4) + (seq ^ (kb & 7))) << 3;
}

// ---- dual-dtype input readers (inputs may be f32 or bf16; no staging) ----
static __device__ __forceinline__ float ld1(const void* p, int i, bool isbf) {
    return isbf ? bf2f(((const ushort_t*)p)[i]) : ((const float*)p)[i];
}
template<bool ISBF>
static __device__ __forceinline__ float ld1t(const void* p, int i) {
    if constexpr (ISBF) return bf2f(((const ushort_t*)p)[i]);
    else return ((const float*)p)[i];
}
static __device__ __forceinline__ short8 load_frag_any(const void* p, int off,
                                                       float s, bool isbf) {
    short8 o;
    if (isbf) {
        uint4 r = *(const uint4*)((const ushort_t*)p + off);
        unsigned aa[4] = {r.x, r.y, r.z, r.w};
#pragma unroll
        for (int i = 0; i < 4; ++i) {
            o[2 * i]     = (short)f2bf(bf2f((ushort_t)(aa[i] & 0xffffu)) * s);
            o[2 * i + 1] = (short)f2bf(bf2f((ushort_t)(aa[i] >> 16)) * s);
        }
    } else {
        const float* f = (const float*)p + off;   // off multiple of 8 -> 32B aligned
        float4 a = *(const float4*)f, b = *(const float4*)(f + 4);
        o[0] = (short)f2bf(a.x * s); o[1] = (short)f2bf(a.y * s);
        o[2] = (short)f2bf(a.z * s); o[3] = (short)f2bf(a.w * s);
        o[4] = (short)f2bf(b.x * s); o[5] = (short)f2bf(b.y * s);
        o[6] = (short)f2bf(b.z * s); o[7] = (short)f2bf(b.w * s);
    }
    return o;
}

// ---------------- K1: fused 4-layer GRU + out-FC + sigmoid ----------------
// Round-0 structure (best measured: 91.9 us) with raw-input prologue.
// Orientation: A=weights (m=gate-col), B=activations (n=seq).
// D[col][seq]: lane holds seq = lane&15, cols = jb + 4*quad + i.
// Per-block dtype self-detection (replaces the deleted convert_kernel);
// block 0 publishes the flag for the downstream kernels.
template<bool ISBF>
static __device__ __forceinline__ void gru_fill(short8* Xs8, const void* x,
        const void* fcw, const void* fcb, int n0, int tid)
{
#pragma unroll 1
    for (int ii = 0; ii < 16; ++ii) {
        int cid = ii * 256 + tid;
        int seq = cid & 15, kb = (cid >> 4) & 7, t = cid >> 7;
        int n = n0 + seq; if (n > NSEQ - 1) n = NSEQ - 1;
        int b = n / NSLOW, s = n - b * NSLOW;
        float xv = ld1t<ISBF>(x, b * T_LEN + s * 16 + t);
        short8 v;
#pragma unroll
        for (int i = 0; i < 8; ++i) {
            int g = kb * 8 + i;
            float h = fmaf(xv, ld1t<ISBF>(fcw, g), ld1t<ISBF>(fcb, g));
            h = h > 0.f ? h : 0.f;
            v[i] = (short)f2bf(h);
        }
        Xs8[xoff(t, kb, seq) >> 3] = v;
    }
}

__global__ __launch_bounds__(256, 2) void gru_kernel(
    const void* __restrict__ x, const void* __restrict__ fcw,
    const void* __restrict__ fcb, const void* __restrict__ wih,
    const void* __restrict__ whh, const void* __restrict__ bih,
    const void* __restrict__ bhh, const void* __restrict__ ofw,
    const void* __restrict__ ofb, int* __restrict__ flag,
    float* __restrict__ Aslow, float* __restrict__ gslow)
{
    __shared__ short8 Xs8[4096];   // 64 KB: 16 seq x 32 t x 64 feat, swizzled
    __shared__ int scnt;
    short* Xs = (short*)Xs8;
    const int tid = threadIdx.x;

    // ---- per-block dtype detection on the first 256 ushorts of x ----
    if (tid == 0) scnt = 0;
    __syncthreads();
    {
        ushort_t u = ((const ushort_t*)x)[tid];
        int e = (u >> 7) & 0xFF;
        int ok = (e >= 80 && e <= 141) ? 1 : 0;
#pragma unroll
        for (int d = 1; d < 64; d <<= 1) ok += __shfl_xor(ok, d, 64);
        if ((tid & 63) == 0) atomicAdd(&scnt, ok);
    }
    __syncthreads();
    const bool isbf = (scnt >= 224);   // bf16 data: ~256/256 sane exponents
    if (blockIdx.x == 0 && tid == 0) *flag = isbf ? 1 : 0;

    const int w = tid >> 6, lane = tid & 63;
    const int q = lane >> 4, m = lane & 15;
    const int jb = w * 16;
    const int n0 = blockIdx.x * 16;

    // ---- fill layer-0 input: relu(x_s * fc_in_w + fc_in_b) ----
    if (isbf) gru_fill<true>(Xs8, x, fcw, fcb, n0, tid);
    else      gru_fill<false>(Xs8, x, fcw, fcb, n0, tid);

    const int col0 = jb + 4 * q;            // this lane's 4 gate-cols
    const int kbw = (col0 >> 3);            // write feature-block
    const int wsub = (col0 & 7);            // 0 or 4
    const int kofs = q * 8;
    const int wbase0 = ((kbw << 4) + (m ^ (kbw & 7))) * 8 + wsub;

    float hc[4];
#pragma unroll 1
    for (int l = 0; l < NL; ++l) {
        const int wb0 = l * G3 * GH;        // element offsets into wih/whh
        // A-frags (weights): lane m = gate-col jb+m, k contiguous
        short8 wR0 = load_frag_any(wih, wb0 + (0 * 64 + jb + m) * 64 + kofs, -L2E, isbf);
        short8 wR1 = load_frag_any(wih, wb0 + (0 * 64 + jb + m) * 64 + 32 + kofs, -L2E, isbf);
        short8 wZ0 = load_frag_any(wih, wb0 + (1 * 64 + jb + m) * 64 + kofs, -L2E, isbf);
        short8 wZ1 = load_frag_any(wih, wb0 + (1 * 64 + jb + m) * 64 + 32 + kofs, -L2E, isbf);
        short8 wN0 = load_frag_any(wih, wb0 + (2 * 64 + jb + m) * 64 + kofs, 2.f * L2E, isbf);
        short8 wN1 = load_frag_any(wih, wb0 + (2 * 64 + jb + m) * 64 + 32 + kofs, 2.f * L2E, isbf);
        short8 uR0 = load_frag_any(whh, wb0 + (0 * 64 + jb + m) * 64 + kofs, -L2E, isbf);
        short8 uR1 = load_frag_any(whh, wb0 + (0 * 64 + jb + m) * 64 + 32 + kofs, -L2E, isbf);
        short8 uZ0 = load_frag_any(whh, wb0 + (1 * 64 + jb + m) * 64 + kofs, -L2E, isbf);
        short8 uZ1 = load_frag_any(whh, wb0 + (1 * 64 + jb + m) * 64 + 32 + kofs, -L2E, isbf);
        short8 uN0 = load_frag_any(whh, wb0 + (2 * 64 + jb + m) * 64 + kofs, 2.f * L2E, isbf);
        short8 uN1 = load_frag_any(whh, wb0 + (2 * 64 + jb + m) * 64 + 32 + kofs, 2.f * L2E, isbf);

        f32x4 bRv, bZv, bNXv, bNHv;
#pragma unroll
        for (int i = 0; i < 4; ++i) {
            int c = col0 + i;
            bRv[i]  = -L2E * (ld1(bih, l * G3 + c, isbf) + ld1(bhh, l * G3 + c, isbf));
            bZv[i]  = -L2E * (ld1(bih, l * G3 + 64 + c, isbf) + ld1(bhh, l * G3 + 64 + c, isbf));
            bNXv[i] = 2.f * L2E * ld1(bih, l * G3 + 128 + c, isbf);
            bNHv[i] = 2.f * L2E * ld1(bhh, l * G3 + 128 + c, isbf);
        }

        hc[0] = hc[1] = hc[2] = hc[3] = 0.f;

        __syncthreads();                    // layer input fully written
        int iA = xoff(0, q, m) >> 3;        // kb=q chain (+128/t)
        int iB = xoff(0, 4 + q, m) >> 3;    // kb=4+q chain
        int wb = wbase0;

        // ---- t = 0 peeled: h=0, gates from xacc only ----
        short8 cx0 = Xs8[iA], cx1 = Xs8[iB];          // X(0)
        short8 nx0 = Xs8[iA + 128], nx1 = Xs8[iB + 128]; // X(1)
        f32x4 xR = bRv, xZ = bZv, xN = bNXv;
        xR = mfma16(wR0, cx0, xR); xR = mfma16(wR1, cx1, xR);
        xZ = mfma16(wZ0, cx0, xZ); xZ = mfma16(wZ1, cx1, xZ);
        xN = mfma16(wN0, cx0, xN); xN = mfma16(wN1, cx1, xN);
#pragma unroll
        for (int i = 0; i < 4; ++i) {
            float r = __builtin_amdgcn_rcpf(1.f + __builtin_amdgcn_exp2f(xR[i]));
            float z = __builtin_amdgcn_rcpf(1.f + __builtin_amdgcn_exp2f(xZ[i]));
            float yp = fmaf(r, bNHv[i], xN[i]);
            float nn = fmaf(-2.f,
                __builtin_amdgcn_rcpf(1.f + __builtin_amdgcn_exp2f(yp)), 1.f);
            hc[i] = fmaf(z, hc[i] - nn, nn);
        }
        *(uint2*)(Xs + wb) = make_uint2(pk2bf(hc[0], hc[1]), pk2bf(hc[2], hc[3]));
        // xacc(1) in barrier shadow
        xR = bRv; xZ = bZv; xN = bNXv;
        xR = mfma16(wR0, nx0, xR); xR = mfma16(wR1, nx1, xR);
        xZ = mfma16(wZ0, nx0, xZ); xZ = mfma16(wZ1, nx1, xZ);
        xN = mfma16(wN0, nx0, xN); xN = mfma16(wN1, nx1, xN);
        iA += 128; iB += 128; wb += 1024;

#pragma unroll 1
        for (int t = 1; t < 32; ++t) {
            __syncthreads();                // h(t-1) visible
            short8 bh0 = Xs8[iA - 128];     // h(t-1), slot t-1
            short8 bh1 = Xs8[iB - 128];
            short8 px0, px1;
            if (t < 31) {                   // X(t+1), slot t+1 (untouched)
                px0 = Xs8[iA + 128];
                px1 = Xs8[iB + 128];
            }
            f32x4 aR = xR, aZ = xZ, aNH = bNHv;
            aR  = mfma16(uR0, bh0, aR);  aR  = mfma16(uR1, bh1, aR);
            aZ  = mfma16(uZ0, bh0, aZ);  aZ  = mfma16(uZ1, bh1, aZ);
            aNH = mfma16(uN0, bh0, aNH); aNH = mfma16(uN1, bh1, aNH);
#pragma unroll
            for (int i = 0; i < 4; ++i) {
                float r = __builtin_amdgcn_rcpf(1.f + __builtin_amdgcn_exp2f(aR[i]));
                float z = __builtin_amdgcn_rcpf(1.f + __builtin_amdgcn_exp2f(aZ[i]));
                float yp = fmaf(r, aNH[i], xN[i]);
                float nn = fmaf(-2.f,
                    __builtin_amdgcn_rcpf(1.f + __builtin_amdgcn_exp2f(yp)), 1.f);
                hc[i] = fmaf(z, hc[i] - nn, nn);
            }
            *(uint2*)(Xs + wb) =
                make_uint2(pk2bf(hc[0], hc[1]), pk2bf(hc[2], hc[3]));
            if (t < 31) {                   // xacc(t+1), barrier shadow
                xR = bRv; xZ = bZv; xN = bNXv;
                xR = mfma16(wR0, px0, xR); xR = mfma16(wR1, px1, xR);
                xZ = mfma16(wZ0, px0, xZ); xZ = mfma16(wZ1, px1, xZ);
                xN = mfma16(wN0, px0, xN); xN = mfma16(wN1, px1, xN);
            }
            iA += 128; iB += 128; wb += 1024;
        }
    }

    // ---- epilogue: eps = h_last @ out_fc_w^T + b ----
    __syncthreads();
    short8 aL0 = Xs8[xoff(31, q, m) >> 3];
    short8 aL1 = Xs8[xoff(31, 4 + q, m) >> 3];
    float sc = (w < 2) ? -L2E : 1.f;
    short8 o0 = load_frag_any(ofw, (jb + m) * 64 + kofs, sc, isbf);
    short8 o1 = load_frag_any(ofw, (jb + m) * 64 + 32 + kofs, sc, isbf);
    f32x4 aE = {ld1(ofb, col0, isbf) * sc, ld1(ofb, col0 + 1, isbf) * sc,
                ld1(ofb, col0 + 2, isbf) * sc, ld1(ofb, col0 + 3, isbf) * sc};
    aE = mfma16(o0, aL0, aE);
    aE = mfma16(o1, aL1, aE);
    int n = n0 + m;           // pad rows land in rows < 8192: harmless
    if (w < 2) {
        f32x4 v;
#pragma unroll
        for (int i = 0; i < 4; ++i)
            v[i] = __builtin_amdgcn_rcpf(1.f + __builtin_amdgcn_exp2f(aE[i]));
        *(f32x4*)(Aslow + n * HID + col0) = v;
    } else {
        *(f32x4*)(gslow + n * HID + (col0 - 32)) = aE;
    }
}

// ---------------- K2: per-chunk (prod A, partial sum), 256 chunks ----------
// P/S stored TRANSPOSED [b][c][h] so pass2's inline prefix fold coalesces.
template<bool ISBF>
static __device__ __forceinline__ void pass1_body(
    const void* x, const float* Aslow, const float* gslow,
    const void* finw, const void* finb, float* P, float* S)
{
    int gt = blockIdx.x * 256 + threadIdx.x;    // 32768 = 4b * 256c * 32h
    int h = gt & 31, c = (gt >> 5) & 255, b = gt >> 13;
    float fw = ld1t<ISBF>(finw, h), fb = ld1t<ISBF>(finb, h);
    float Pv = 1.f, Sv = 0.f;
    int t0 = c * 128;
#pragma unroll 1
    for (int seg = 0; seg < 8; ++seg) {
        int sidx = (t0 >> 4) + seg - 1;
        if (sidx < 0) sidx = 0;
        if (sidx > NSLOW - 1) sidx = NSLOW - 1;
        float A = Aslow[(b * NSLOW + sidx) * HID + h];
        float g = gslow[(b * NSLOW + sidx) * HID + h];
        float fwg = fw * g, fbg = fb * g;
        float xs[16];
        if constexpr (ISBF) {
            const uint4* px = (const uint4*)((const ushort_t*)x + b * T_LEN + t0 + seg * 16);
            uint4 ra = px[0], rb = px[1];
            unsigned xa[8] = {ra.x, ra.y, ra.z, ra.w, rb.x, rb.y, rb.z, rb.w};
#pragma unroll
            for (int j = 0; j < 8; ++j) {
                xs[2 * j]     = bf2f((ushort_t)(xa[j] & 0xffffu));
                xs[2 * j + 1] = bf2f((ushort_t)(xa[j] >> 16));
            }
        } else {
            const float4* px = (const float4*)((const float*)x + b * T_LEN + t0 + seg * 16);
#pragma unroll
            for (int k = 0; k < 4; ++k) {
                float4 v = px[k];
                xs[4 * k] = v.x; xs[4 * k + 1] = v.y;
                xs[4 * k + 2] = v.z; xs[4 * k + 3] = v.w;
            }
        }
#pragma unroll
        for (int j = 0; j < 16; ++j)
            Sv = fmaf(A, Sv, fmaf(xs[j], fwg, fbg));
        float A2 = A * A, A4 = A2 * A2, A8 = A4 * A4;
        Pv *= A8 * A8;
    }
    P[(b * NCH + c) * HID + h] = Pv;
    S[(b * NCH + c) * HID + h] = Sv;
}

__global__ __launch_bounds__(256) void pass1_kernel(
    const void* __restrict__ x, const float* __restrict__ Aslow,
    const float* __restrict__ gslow, const void* __restrict__ finw,
    const void* __restrict__ finb, const int* __restrict__ flag,
    float* __restrict__ P, float* __restrict__ S)
{
    if (*flag) pass1_body<true>(x, Aslow, gslow, finw, finb, P, S);
    else       pass1_body<false>(x, Aslow, gslow, finw, finb, P, S);
}

// ---------------- K3: recompute states + fused output dot ----------------
// Inline chunk-prefix fold (replaces the single-block scan kernel + Hpre).
template<bool ISBF>
static __device__ __forceinline__ void pass2_body(
    const void* x, const float* Aslow, const float* gslow,
    const float* P, const float* S, const void* finw, const void* finb,
    const void* fow, const void* fob, void* outv)
{
    int wv = blockIdx.x * 4 + (threadIdx.x >> 6);   // 0..511
    int lane = threadIdx.x & 63;
    int half = lane >> 5, h = lane & 31;
    int pair = wv * 2 + half;                       // 0..1023 = b*NCH + c
    int b = pair >> 8, c = pair & 255;
    ushort_t* outb = (ushort_t*)outv;
    float* outf = (float*)outv;
    float fw = ld1t<ISBF>(finw, h), fb = ld1t<ISBF>(finb, h);
    float wo = ld1t<ISBF>(fow, h), ob = ld1t<ISBF>(fob, 0);

    // prefix over chunk summaries 0..c-1 (coalesced: lanes stride h)
    float hv = 0.f;
    const float* Pb = P + b * NCH * HID + h;
    const float* Sb = S + b * NCH * HID + h;
#pragma unroll 4
    for (int j = 0; j < c; ++j)
        hv = fmaf(Pb[j * HID], hv, Sb[j * HID]);

    int t0 = c * 128;
#pragma unroll 1
    for (int blk = 0; blk < 4; ++blk) {
        float ykeep = 0.f;
        float A = 0.f, fwg = 0.f, fbg = 0.f;
#pragma unroll
        for (int tt = 0; tt < 32; ++tt) {
            int t = t0 + blk * 32 + tt;
            if ((tt & 15) == 0) {
                int sidx = (t >> 4) - 1;
                if (sidx < 0) sidx = 0;
                A = Aslow[(b * NSLOW + sidx) * HID + h];
                float g = gslow[(b * NSLOW + sidx) * HID + h];
                fwg = fw * g; fbg = fb * g;
            }
            float xv = ld1t<ISBF>(x, b * T_LEN + t);
            hv = fmaf(A, hv, fmaf(xv, fwg, fbg));
            float y = hv * wo;
            y += __shfl_xor(y, 1, 64);
            y += __shfl_xor(y, 2, 64);
            y += __shfl_xor(y, 4, 64);
            y += __shfl_xor(y, 8, 64);
            y += __shfl_xor(y, 16, 64);
            if (tt == h) ykeep = y + ob;
        }
        int oidx = b * T_LEN + t0 + blk * 32 + h;
        if constexpr (ISBF) outb[oidx] = f2bf(ykeep);
        else                outf[oidx] = ykeep;
    }
}

__global__ __launch_bounds__(256) void pass2_kernel(
    const void* __restrict__ x, const float* __restrict__ Aslow,
    const float* __restrict__ gslow, const float* __restrict__ P,
    const float* __restrict__ S, const void* __restrict__ finw,
    const void* __restrict__ finb, const void* __restrict__ fow,
    const void* __restrict__ fob, const int* __restrict__ flag,
    void* __restrict__ outv)
{
    if (*flag) pass2_body<true>(x, Aslow, gslow, P, S, finw, finb, fow, fob, outv);
    else       pass2_body<false>(x, Aslow, gslow, P, S, finw, finb, fow, fob, outv);
}

extern "C" void kernel_launch(void* const* d_in, const int* in_sizes, int n_in,
                              void* d_out, int out_size, void* d_ws, size_t ws_size,
                              hipStream_t stream)
{
    const void* x    = d_in[0];
    const void* fcw  = d_in[1];
    const void* fcb  = d_in[2];
    const void* wih  = d_in[3];
    const void* whh  = d_in[4];
    const void* bih  = d_in[5];
    const void* bhh  = d_in[6];
    const void* ofw  = d_in[7];
    const void* ofb  = d_in[8];
    const void* finw = d_in[9];
    const void* finb = d_in[10];
    const void* fow  = d_in[11];
    const void* fob  = d_in[12];

    float* Aslow = (float*)((char*)d_ws + CONV_PAD_BYTES);  // 8192*32 f32
    float* gslow = Aslow + 8192 * 32;
    float* P     = gslow + 8192 * 32;          // [b][c][h]
    float* S     = P + 4 * 32 * NCH;
    float* Hpre  = S + 4 * 32 * NCH;           // unused (kept for ws layout)
    int*   flag  = (int*)(Hpre + 4 * 32 * NCH);

    gru_kernel<<<dim3(512), dim3(256), 0, stream>>>(
        x, fcw, fcb, wih, whh, bih, bhh, ofw, ofb, flag, Aslow, gslow);
    pass1_kernel<<<dim3(128), dim3(256), 0, stream>>>(
        x, Aslow, gslow, finw, finb, flag, P, S);
    pass2_kernel<<<dim3(128), dim3(256), 0, stream>>>(
        x, Aslow, gslow, P, S, finw, finb, fow, fob, flag, d_out);
}